// Round 15
// baseline (75.353 us; speedup 1.0000x reference)
//
#include <hip/hip_runtime.h>
#include <hip/hip_fp16.h>
#include <math.h>

#define BB 512
#define LL 10
#define RR 2048
#define DD 256
#define KK 20
#define HH 128
#define NVOCAB 30000
#define GEOD 64

#define FP8_SCALE   64.0f
#define FP8_DESCALE (1.0f / 4096.0f)

// workspace layout (bytes)
#define EMB8_BYTES (NVOCAB * DD)            // 7,680,000
#define BLOB1_OFF  EMB8_BYTES               // u16[4096]  = 8192 B
#define BLOB2_OFF  (BLOB1_OFF + 8192)       // u16[16384] = 32768 B
#define W3T_OFF    (BLOB2_OFF + 32768)      // f32[2560]  = 10240 B
#define W5T_OFF    (W3T_OFF + 10240)        // f32[2048]  = 8192 B
#define SORT_OFF   (W5T_OFF + 8192)         // u16[B*RR]  = 2,097,152 B

typedef __attribute__((ext_vector_type(2))) long long llx2;
typedef __attribute__((ext_vector_type(4))) float f32x4;
typedef __attribute__((ext_vector_type(8))) short bf16x8;

static __device__ inline unsigned short f2bf(float f) {
    unsigned u = __float_as_uint(f);
    unsigned r = (u + 0x7fff + ((u >> 16) & 1)) >> 16;   // RNE
    return (unsigned short)r;
}

// ------- Kernel PRE: normalize (permuted fp8) + weight prep + doc sort ------
__global__ __launch_bounds__(256) void pre_kernel(
    const float* __restrict__ emb,
    const float* __restrict__ w_m0, const float* __restrict__ w_m1,
    const float* __restrict__ w3,   const float* __restrict__ w5,
    const int*   __restrict__ text_right,
    unsigned char* __restrict__ emb8,
    unsigned short* __restrict__ blob1, unsigned short* __restrict__ blob2,
    float* __restrict__ w3T, float* __restrict__ w5T,
    unsigned short* __restrict__ sortd)
{
    __shared__ unsigned s_cnt[256];
    __shared__ unsigned s_off[257];

    if (blockIdx.x < 7500) {
        int row  = blockIdx.x * 4 + (threadIdx.x >> 6);
        int lane = threadIdx.x & 63;
        // permuted byte p = q*64 + kk*8 + t  <-  element e = kk*32 + q*8 + t
        int e0 = ((lane >> 1) & 7) * 32 + (lane >> 4) * 8 + (lane & 1) * 4;
        float4 v = *(const float4*)(emb + (size_t)row * DD + e0);
        float ssq = v.x * v.x + v.y * v.y + v.z * v.z + v.w * v.w;
        #pragma unroll
        for (int off = 32; off; off >>= 1) ssq += __shfl_xor(ssq, off);
        float s = FP8_SCALE / fmaxf(sqrtf(ssq), 1e-12f);
        unsigned pk = 0;
        pk = (unsigned)__builtin_amdgcn_cvt_pk_fp8_f32(v.x * s, v.y * s, (int)pk, false);
        pk = (unsigned)__builtin_amdgcn_cvt_pk_fp8_f32(v.z * s, v.w * s, (int)pk, true);
        ((unsigned*)(emb8 + (size_t)row * DD))[lane] = pk;
    } else if (blockIdx.x < 7598) {
        int i = (blockIdx.x - 7500) * 256 + threadIdx.x;
        if (i < 4096) {                       // layer-1 B fragments: [t][lane][8]
            int t = i >> 9, ln = (i >> 3) & 63, tt = i & 7;
            int n = t * 16 + (ln & 15), k = (ln >> 4) * 8 + tt;
            blob1[i] = (k < KK) ? f2bf(w_m0[k * HH + n]) : (unsigned short)0;
        } else if (i < 4096 + 16384) {        // layer-2 B fragments: [ks][t][lane][8]
            int i2 = i - 4096;
            int ks = i2 >> 12, rem = i2 & 4095;
            int t = rem >> 9, ln = (rem >> 3) & 63, tt = rem & 7;
            int n = t * 16 + (ln & 15), k = ks * 32 + (ln >> 4) * 8 + tt;
            blob2[i2] = f2bf(w_m1[k * HH + n]);
        } else if (i < 4096 + 16384 + 2560) { // w3T[10][256]
            int i3 = i - (4096 + 16384);
            int j = i3 >> 8, d = i3 & 255;
            w3T[i3] = w3[d * 10 + j];
        } else if (i < 4096 + 16384 + 2560 + 2048) { // w5T[32][64]
            int i4 = i - (4096 + 16384 + 2560);
            int c = i4 >> 6, d = i4 & 63;
            w5T[i4] = w5[d * 32 + c];
        }
    } else {
        // ---- per-batch counting sort of doc ids (bucket id>>7) ----
        int b   = blockIdx.x - 7598;
        int tid = threadIdx.x;
        if (tid < 256) s_cnt[tid] = 0u;
        __syncthreads();
        const int* trb = text_right + b * RR;
        int dv[8];
        #pragma unroll
        for (int i = 0; i < 8; ++i) {
            dv[i] = trb[tid * 8 + i];
            atomicAdd(&s_cnt[dv[i] >> 7], 1u);
        }
        __syncthreads();
        if (tid < 256) s_off[tid + 1] = s_cnt[tid];
        if (tid == 0) s_off[0] = 0u;
        __syncthreads();
        #pragma unroll 1
        for (int st = 1; st < 256; st <<= 1) {
            unsigned v = 0u;
            if (tid < 256 && tid + 1 > st) v = s_off[tid + 1 - st];
            __syncthreads();
            if (tid < 256 && tid + 1 > st) s_off[tid + 1] += v;
            __syncthreads();
        }
        unsigned short* dst = sortd + (size_t)b * RR;
        #pragma unroll
        for (int i = 0; i < 8; ++i) {
            unsigned p = atomicAdd(&s_off[dv[i] >> 7], 1u);
            dst[p] = (unsigned short)dv[i];
        }
    }
}

static __device__ inline unsigned wave_umax_u32(unsigned x)
{
    unsigned t;
    t = (unsigned)__builtin_amdgcn_update_dpp((int)x, (int)x, 0x111, 0xF, 0xF, false); x = x > t ? x : t;
    t = (unsigned)__builtin_amdgcn_update_dpp((int)x, (int)x, 0x112, 0xF, 0xF, false); x = x > t ? x : t;
    t = (unsigned)__builtin_amdgcn_update_dpp((int)x, (int)x, 0x114, 0xF, 0xF, false); x = x > t ? x : t;
    t = (unsigned)__builtin_amdgcn_update_dpp((int)x, (int)x, 0x118, 0xF, 0xF, false); x = x > t ? x : t;
    t = (unsigned)__builtin_amdgcn_update_dpp((int)x, (int)x, 0x142, 0xF, 0xF, false); x = x > t ? x : t;
    t = (unsigned)__builtin_amdgcn_update_dpp((int)x, (int)x, 0x143, 0xF, 0xF, false); x = x > t ? x : t;
    return (unsigned)__builtin_amdgcn_readlane((int)x, 63);
}

// per-lane top-2 packed keys over 32 strided slots (2048-wide row)
static __device__ inline void build_top2(const unsigned short* __restrict__ row,
                                         int lane, unsigned extmask,
                                         unsigned& k1, unsigned& k2)
{
    unsigned m1 = 0u, m2 = 0u;
    #pragma unroll
    for (int k = 0; k < 32; ++k) {
        int j = lane + 64 * k;
        unsigned key = ((unsigned)row[j] << 16) | (unsigned)(2047 - j);
        key = ((extmask >> k) & 1u) ? 0u : key;
        unsigned mn = m1 < key ? m1 : key;   // v_min_u32
        m1 = m1 > key ? m1 : key;            // v_max_u32
        m2 = m2 > mn ? m2 : mn;              // v_max_u32
    }
    k1 = m1; k2 = m2;
}

// ---------------- Kernel B: fused per-batch pipeline (16 waves) -------------
__global__ __launch_bounds__(1024, 4) void fused_kernel(
    const int*   __restrict__ text_left,
    const int*   __restrict__ loc_left,
    const float* __restrict__ distance,
    const float* __restrict__ emb,
    const float* __restrict__ attn_w,
    const float* __restrict__ b_m0, const float* __restrict__ b_m1,
    const float* __restrict__ w_m2, const float* __restrict__ b_m2,
    const float* __restrict__ out_w, const float* __restrict__ out_b,
    const float* __restrict__ lat_tab, const float* __restrict__ lon_tab,
    const float* __restrict__ b3, const float* __restrict__ b5,
    const float* __restrict__ w4, const float* __restrict__ b4,
    const unsigned char*  __restrict__ emb8,   // permuted fp8 table
    const unsigned short* __restrict__ blob1,
    const unsigned short* __restrict__ blob2,
    const float* __restrict__ w3T, const float* __restrict__ w5T,
    const unsigned short* __restrict__ sortd,  // per-batch sorted doc ids
    float*       __restrict__ out)
{
    // arena: phase B = 16 waves x 2KB stage; phase C/D overlay = h1 + topk
    __shared__ __align__(16) unsigned char arena[32768];
    __shared__ __align__(16) unsigned short s_keys[LL][RR];   // 40 KB
    __shared__ float s_logit[LL];
    __shared__ float s_h[16];
    __shared__ float s_feat[164];

    unsigned short* s_h1   = (unsigned short*)arena;          // 4 KB (phase D)
    float*          s_topk = (float*)(arena + 4096);          // 2 KB (phase C/D)

    const int b    = blockIdx.x;
    const int tid  = threadIdx.x;
    const int lane = tid & 63;
    const int wid  = tid >> 6;        // 0..15
    const int m15  = lane & 15, q = lane >> 4;

    // ========= phase B: 2-substep staged fp8 GEMM, 16 waves x 8 tiles =======
    {
        llx2 afr[4];
        {
            int qidx = (m15 < LL) ? text_left[b * LL + m15] : 0;
            const unsigned char* ap = emb8 + (size_t)qidx * DD + q * 64;
            #pragma unroll
            for (int s = 0; s < 4; ++s) afr[s] = *(const llx2*)(ap + s * 16);
        }
        const int dslot = lane >> 2;   // doc within tile (0..15)
        const int dsub  = lane & 3;    // 32B sub-chunk within 128B

        // preload this wave's 8 tile id sets (static indices)
        int docs[8];
        {
            const unsigned short* sb = sortd + (size_t)b * RR;
            #pragma unroll
            for (int i = 0; i < 8; ++i)
                docs[i] = (int)sb[(wid + 16 * i) * 16 + dslot];
        }

        unsigned char* stg = arena + wid * 2048;   // per-wave private 2KB

        llx2 P0, P1;   // 32B register row buffer

        auto GLOAD = [&](int doc, int g) {
            const unsigned char* p = emb8 + (size_t)doc * DD + g * 128 + dsub * 32;
            P0 = *(const llx2*)(p);
            P1 = *(const llx2*)(p + 16);
        };
        auto SWRITE = [&]() {          // linear: lane*32
            *(llx2*)(stg + lane * 32)      = P0;
            *(llx2*)(stg + lane * 32 + 16) = P1;
        };
        auto SUBMFMA = [&](int g, f32x4& acc) {
            llx2 b0 = *(const llx2*)(stg + m15 * 128 + q * 16);
            llx2 b1 = *(const llx2*)(stg + m15 * 128 + 64 + q * 16);
            int s0 = 2 * g, s1 = 2 * g + 1;
            acc = __builtin_amdgcn_mfma_f32_16x16x32_fp8_fp8(afr[s0][0], b0[0], acc, 0, 0, 0);
            acc = __builtin_amdgcn_mfma_f32_16x16x32_fp8_fp8(afr[s0][1], b0[1], acc, 0, 0, 0);
            acc = __builtin_amdgcn_mfma_f32_16x16x32_fp8_fp8(afr[s1][0], b1[0], acc, 0, 0, 0);
            acc = __builtin_amdgcn_mfma_f32_16x16x32_fp8_fp8(afr[s1][1], b1[1], acc, 0, 0, 0);
        };

        GLOAD(docs[0], 0);                         // prologue
        #pragma unroll
        for (int i = 0; i < 8; ++i) {
            f32x4 acc = {0.f, 0.f, 0.f, 0.f};
            SWRITE();                              // stage g=0
            GLOAD(docs[i], 1);                     // prefetch g=1
            SUBMFMA(0, acc);
            SWRITE();                              // stage g=1
            if (i < 7) GLOAD(docs[i + 1], 0);      // prefetch next tile g=0
            SUBMFMA(1, acc);
            int n0 = (wid + 16 * i) * 16;
            #pragma unroll
            for (int v = 0; v < 4; ++v) {
                int m = q * 4 + v;
                if (m < LL) {
                    float sc = acc[v] * FP8_DESCALE;
                    unsigned hb = (unsigned)__half_as_ushort(__float2half(sc));
                    unsigned ok = hb ^ ((hb & 0x8000u) ? 0xFFFFu : 0x8000u);
                    s_keys[m][n0 + m15] = (unsigned short)ok;
                }
            }
        }
    }
    __syncthreads();

    // pad-init topk cells never written by TOPK (rows>=10 or cols>=20)
    if (tid < 512) {
        int row = tid >> 5, col = tid & 31;
        if (row >= LL || col >= KK) s_topk[row * 32 + col] = 0.f;
    }

    // ====== phase C: top-k rows 0-9 on waves 0-9; aux on waves 10-13 ========
    if (wid < LL) {
        const int l = wid;
        const unsigned short* krow = &s_keys[l][0];
        unsigned extmask = 0u, k1, k2;
        build_top2(krow, lane, extmask, k1, k2);
        #pragma unroll 1
        for (int it = 0; it < KK; ++it) {
            unsigned bmk = wave_umax_u32(k1);
            if (k1 == bmk) {                  // unique owner (keys unique)
                unsigned o16 = bmk >> 16;
                unsigned hbv = (o16 & 0x8000u) ? (o16 & 0x7FFFu) : (o16 ^ 0xFFFFu);
                s_topk[l * 32 + it] = __half2float(__ushort_as_half((unsigned short)hbv));
                int j = 2047 - (int)(bmk & 0xFFFFu);
                extmask |= 1u << (j >> 6);
                k1 = k2; k2 = 0u;
            }
            if (__any(k1 == 0u)) {
                if (k1 == 0u) build_top2(krow, lane, extmask, k1, k2);
            }
        }
    } else if (wid == 10 || wid == 11) {
        // q1 projection features
        int p = (wid - 10) * 64 + lane;
        if (p < 100) {
            int l = p / 10, j = p % 10;
            int v = text_left[b * LL + l];
            const float4* qr = (const float4*)(emb + (size_t)v * DD);
            const float4* wr = (const float4*)(w3T + j * DD);
            float a = b3[j];
            #pragma unroll 8
            for (int d4 = 0; d4 < 64; ++d4) {
                float4 qv = qr[d4], wv = wr[d4];
                a += qv.x * wv.x + qv.y * wv.y + qv.z * wv.z + qv.w * wv.w;
            }
            s_feat[p] = a;
        }
    } else if (wid == 12) {
        // attention logits
        const float4 aw = *(const float4*)(attn_w + lane * 4);
        for (int l = 0; l < LL; ++l) {
            int v = text_left[b * LL + l];
            float4 qv = *(const float4*)(emb + (size_t)v * DD + lane * 4);
            float d = qv.x * aw.x + qv.y * aw.y + qv.z * aw.z + qv.w * aw.w;
            #pragma unroll
            for (int off = 32; off; off >>= 1) d += __shfl_xor(d, off);
            if (lane == 0) s_logit[l] = (v == 0) ? -INFINITY : d;
        }
    } else if (wid == 13) {
        // geo features
        int c = lane & 31, which = lane >> 5;
        int v = loc_left[b * 2 + which];
        const float* tab = which ? lon_tab : lat_tab;
        const float4* tr = (const float4*)(tab + (size_t)v * GEOD);
        const float4* wr = (const float4*)(w5T + c * GEOD);
        float a = b5[c];
        #pragma unroll
        for (int d4 = 0; d4 < 16; ++d4) {
            float4 tv = tr[d4], wv = wr[d4];
            a += tv.x * wv.x + tv.y * wv.y + tv.z * wv.z + tv.w * wv.w;
        }
        s_feat[100 + which * 32 + c] = a;
    }
    __syncthreads();

    // ================= phase D: MFMA MLP + softmax + output (wave 0) ========
    if (wid == 0) {
        // ---- layer 1: topk[16x32] @ w_m0 -> h1[16x128] ----
        float tv[8];
        *(float4*)(tv)     = *(const float4*)(&s_topk[m15 * 32 + q * 8]);
        *(float4*)(tv + 4) = *(const float4*)(&s_topk[m15 * 32 + q * 8 + 4]);
        bf16x8 a1;
        #pragma unroll
        for (int t = 0; t < 8; ++t) a1[t] = (short)f2bf(tv[t]);
        f32x4 acc1[8];
        #pragma unroll
        for (int t = 0; t < 8; ++t) {
            bf16x8 b1 = *(const bf16x8*)(blob1 + t * 512 + lane * 8);
            f32x4 z = {0.f, 0.f, 0.f, 0.f};
            acc1[t] = __builtin_amdgcn_mfma_f32_16x16x32_bf16(a1, b1, z, 0, 0, 0);
        }
        #pragma unroll
        for (int t = 0; t < 8; ++t) {
            int c = t * 16 + m15;
            float bb0 = b_m0[c];
            #pragma unroll
            for (int v = 0; v < 4; ++v) {
                int m = q * 4 + v;
                float h = tanhf(acc1[t][v] + bb0);
                s_h1[m * 128 + (((c >> 3) ^ m) << 3) + (c & 7)] = f2bf(h);
            }
        }
        // ---- layer 2 ----
        f32x4 acc2[8];
        #pragma unroll
        for (int t = 0; t < 8; ++t) acc2[t] = (f32x4){0.f, 0.f, 0.f, 0.f};
        #pragma unroll
        for (int ks = 0; ks < 4; ++ks) {
            bf16x8 a2 = *(const bf16x8*)(s_h1 + m15 * 128 + (((ks * 4 + q) ^ m15) << 3));
            #pragma unroll
            for (int t = 0; t < 8; ++t) {
                bf16x8 b2 = *(const bf16x8*)(blob2 + (ks * 8 + t) * 512 + lane * 8);
                acc2[t] = __builtin_amdgcn_mfma_f32_16x16x32_bf16(a2, b2, acc2[t], 0, 0, 0);
            }
        }
        // ---- layer 3 + reduce ----
        float part[4] = {0.f, 0.f, 0.f, 0.f};
        #pragma unroll
        for (int t = 0; t < 8; ++t) {
            int c = t * 16 + m15;
            float bb1 = b_m1[c];
            float wm2 = w_m2[c];
            #pragma unroll
            for (int v = 0; v < 4; ++v)
                part[v] += tanhf(acc2[t][v] + bb1) * wm2;
        }
        #pragma unroll
        for (int v = 0; v < 4; ++v) {
            #pragma unroll
            for (int off = 1; off < 16; off <<= 1) part[v] += __shfl_xor(part[v], off);
        }
        if (m15 == 0) {
            #pragma unroll
            for (int v = 0; v < 4; ++v) {
                int m = q * 4 + v;
                if (m < LL) s_h[m] = tanhf(part[v] + b_m2[0]);
            }
        }
        // ---- parallel 164-dot for w0/w1 across the wave ----
        float w0p = 0.f, w1p = 0.f;
        #pragma unroll
        for (int i = lane; i < 164; i += 64) {
            float f = s_feat[i];
            w0p += f * w4[i * 2 + 0];
            w1p += f * w4[i * 2 + 1];
        }
        #pragma unroll
        for (int off = 32; off; off >>= 1) {
            w0p += __shfl_xor(w0p, off);
            w1p += __shfl_xor(w1p, off);
        }
        // ---- softmax + frozen x + final output (lane 0) ----
        if (lane == 0) {
            float mx = -INFINITY;
            #pragma unroll
            for (int l = 0; l < LL; ++l) mx = fmaxf(mx, s_logit[l]);
            float ex[LL];
            float sum = 0.f;
            #pragma unroll
            for (int l = 0; l < LL; ++l) { ex[l] = expf(s_logit[l] - mx); sum += ex[l]; }
            float x = 0.f;
            #pragma unroll
            for (int l = 0; l < LL; ++l) x += s_h[l] * (ex[l] / sum);
            float xo = tanhf(x * out_w[0] + out_b[0]);
            out[b] = (w0p + b4[0]) * xo + (w1p + b4[1]) * distance[b];
        }
    }
}

extern "C" void kernel_launch(void* const* d_in, const int* in_sizes, int n_in,
                              void* d_out, int out_size, void* d_ws, size_t ws_size,
                              hipStream_t stream) {
    const int*   text_left  = (const int*)  d_in[0];
    const int*   text_right = (const int*)  d_in[1];
    const int*   loc_left   = (const int*)  d_in[2];
    const float* distance   = (const float*)d_in[3];
    const float* emb        = (const float*)d_in[4];
    const float* attn_w     = (const float*)d_in[5];
    const float* w_m0       = (const float*)d_in[6];
    const float* b_m0       = (const float*)d_in[7];
    const float* w_m1       = (const float*)d_in[8];
    const float* b_m1       = (const float*)d_in[9];
    const float* w_m2       = (const float*)d_in[10];
    const float* b_m2       = (const float*)d_in[11];
    const float* out_w      = (const float*)d_in[12];
    const float* out_b      = (const float*)d_in[13];
    const float* lat_tab    = (const float*)d_in[14];
    const float* lon_tab    = (const float*)d_in[15];
    const float* w3         = (const float*)d_in[16];
    const float* b3         = (const float*)d_in[17];
    const float* w5         = (const float*)d_in[18];
    const float* b5         = (const float*)d_in[19];
    const float* w4         = (const float*)d_in[20];
    const float* b4         = (const float*)d_in[21];

    unsigned char*  ws    = (unsigned char*)d_ws;
    unsigned char*  emb8  = ws;
    unsigned short* blob1 = (unsigned short*)(ws + BLOB1_OFF);
    unsigned short* blob2 = (unsigned short*)(ws + BLOB2_OFF);
    float*          w3T   = (float*)(ws + W3T_OFF);
    float*          w5T   = (float*)(ws + W5T_OFF);
    unsigned short* sortd = (unsigned short*)(ws + SORT_OFF);
    float*          out   = (float*)d_out;

    pre_kernel<<<8110, 256, 0, stream>>>(emb, w_m0, w_m1, w3, w5, text_right,
                                         emb8, blob1, blob2, w3T, w5T, sortd);

    fused_kernel<<<BB, 1024, 0, stream>>>(
        text_left, loc_left, distance, emb, attn_w,
        b_m0, b_m1, w_m2, b_m2, out_w, out_b,
        lat_tab, lon_tab, b3, b5, w4, b4,
        emb8, blob1, blob2, w3T, w5T, sortd, out);
}

// Round 16
// 50.950 us; speedup vs baseline: 1.4790x; 1.4790x over previous
//
#include <hip/hip_runtime.h>
#include <hip/hip_fp16.h>
#include <math.h>

#define BB 512
#define LL 10
#define RR 2048
#define DD 256
#define KK 20
#define HH 128
#define NVOCAB 30000
#define GEOD 64

#define FP4_SCALE   24.0f
#define FP4_DESCALE (1.0f / 576.0f)   // 1/(24*24)

// workspace layout (bytes)
#define EMB4_BYTES (NVOCAB * 128)           // 3,840,000 (fp4 rows, 128 B each)
#define BLOB1_OFF  EMB4_BYTES               // u16[4096]  = 8192 B
#define BLOB2_OFF  (BLOB1_OFF + 8192)       // u16[16384] = 32768 B
#define W3T_OFF    (BLOB2_OFF + 32768)      // f32[2560]  = 10240 B
#define W5T_OFF    (W3T_OFF + 10240)        // f32[2048]  = 8192 B

typedef __attribute__((ext_vector_type(2))) long long llx2;
typedef __attribute__((ext_vector_type(4))) float f32x4;
typedef __attribute__((ext_vector_type(8))) short bf16x8;
typedef __attribute__((ext_vector_type(8))) int   i32x8;

static __device__ inline unsigned short f2bf(float f) {
    unsigned u = __float_as_uint(f);
    unsigned r = (u + 0x7fff + ((u >> 16) & 1)) >> 16;   // RNE
    return (unsigned short)r;
}

// quantize to fp4 e2m1 nibble (values 0,.5,1,1.5,2,3,4,6 with sign)
static __device__ inline unsigned q_e2m1(float x) {
    unsigned s = (x < 0.f) ? 8u : 0u;
    float a = fabsf(x);
    unsigned c = (a < 0.25f) ? 0u : (a < 0.75f) ? 1u : (a < 1.25f) ? 2u :
                 (a < 1.75f) ? 3u : (a < 2.5f)  ? 4u : (a < 3.5f)  ? 5u :
                 (a < 5.0f)  ? 6u : 7u;
    return s | c;
}

// ---------------- Kernel PRE: normalized fp4 table + weight prep ------------
__global__ __launch_bounds__(256) void pre_kernel(
    const float* __restrict__ emb,
    const float* __restrict__ w_m0, const float* __restrict__ w_m1,
    const float* __restrict__ w3,   const float* __restrict__ w5,
    unsigned char* __restrict__ emb4,
    unsigned short* __restrict__ blob1, unsigned short* __restrict__ blob2,
    float* __restrict__ w3T, float* __restrict__ w5T)
{
    if (blockIdx.x < 7500) {
        int row  = blockIdx.x * 4 + (threadIdx.x >> 6);
        int lane = threadIdx.x & 63;
        float4 v = *(const float4*)(emb + (size_t)row * DD + lane * 4);
        float ssq = v.x * v.x + v.y * v.y + v.z * v.z + v.w * v.w;
        #pragma unroll
        for (int off = 32; off; off >>= 1) ssq += __shfl_xor(ssq, off);
        float s = FP4_SCALE / fmaxf(sqrtf(ssq), 1e-12f);
        unsigned n0 = q_e2m1(v.x * s), n1 = q_e2m1(v.y * s);
        unsigned n2 = q_e2m1(v.z * s), n3 = q_e2m1(v.w * s);
        unsigned short pk = (unsigned short)(n0 | (n1 << 4) | (n2 << 8) | (n3 << 12));
        ((unsigned short*)(emb4 + (size_t)row * 128))[lane] = pk;
    } else {
        int i = (blockIdx.x - 7500) * 256 + threadIdx.x;
        if (i < 4096) {                       // layer-1 B fragments: [t][lane][8]
            int t = i >> 9, ln = (i >> 3) & 63, tt = i & 7;
            int n = t * 16 + (ln & 15), k = (ln >> 4) * 8 + tt;
            blob1[i] = (k < KK) ? f2bf(w_m0[k * HH + n]) : (unsigned short)0;
        } else if (i < 4096 + 16384) {        // layer-2 B fragments: [ks][t][lane][8]
            int i2 = i - 4096;
            int ks = i2 >> 12, rem = i2 & 4095;
            int t = rem >> 9, ln = (rem >> 3) & 63, tt = rem & 7;
            int n = t * 16 + (ln & 15), k = ks * 32 + (ln >> 4) * 8 + tt;
            blob2[i2] = f2bf(w_m1[k * HH + n]);
        } else if (i < 4096 + 16384 + 2560) { // w3T[10][256]
            int i3 = i - (4096 + 16384);
            int j = i3 >> 8, d = i3 & 255;
            w3T[i3] = w3[d * 10 + j];
        } else if (i < 4096 + 16384 + 2560 + 2048) { // w5T[32][64]
            int i4 = i - (4096 + 16384 + 2560);
            int c = i4 >> 6, d = i4 & 63;
            w5T[i4] = w5[d * 32 + c];
        }
    }
}

static __device__ inline unsigned wave_umax_u32(unsigned x)
{
    unsigned t;
    t = (unsigned)__builtin_amdgcn_update_dpp((int)x, (int)x, 0x111, 0xF, 0xF, false); x = x > t ? x : t;
    t = (unsigned)__builtin_amdgcn_update_dpp((int)x, (int)x, 0x112, 0xF, 0xF, false); x = x > t ? x : t;
    t = (unsigned)__builtin_amdgcn_update_dpp((int)x, (int)x, 0x114, 0xF, 0xF, false); x = x > t ? x : t;
    t = (unsigned)__builtin_amdgcn_update_dpp((int)x, (int)x, 0x118, 0xF, 0xF, false); x = x > t ? x : t;
    t = (unsigned)__builtin_amdgcn_update_dpp((int)x, (int)x, 0x142, 0xF, 0xF, false); x = x > t ? x : t;
    t = (unsigned)__builtin_amdgcn_update_dpp((int)x, (int)x, 0x143, 0xF, 0xF, false); x = x > t ? x : t;
    return (unsigned)__builtin_amdgcn_readlane((int)x, 63);
}

// per-lane top-2 packed keys over 32 strided slots (2048-wide row)
static __device__ inline void build_top2(const unsigned short* __restrict__ row,
                                         int lane, unsigned extmask,
                                         unsigned& k1, unsigned& k2)
{
    unsigned m1 = 0u, m2 = 0u;
    #pragma unroll
    for (int k = 0; k < 32; ++k) {
        int j = lane + 64 * k;
        unsigned key = ((unsigned)row[j] << 16) | (unsigned)(2047 - j);
        key = ((extmask >> k) & 1u) ? 0u : key;
        unsigned mn = m1 < key ? m1 : key;   // v_min_u32
        m1 = m1 > key ? m1 : key;            // v_max_u32
        m2 = m2 > mn ? m2 : mn;              // v_max_u32
    }
    k1 = m1; k2 = m2;
}

// ---------------- Kernel B: fused per-batch pipeline (8 waves) --------------
__global__ __launch_bounds__(512, 4) void fused_kernel(
    const int*   __restrict__ text_left,
    const int*   __restrict__ text_right,
    const int*   __restrict__ loc_left,
    const float* __restrict__ distance,
    const float* __restrict__ emb,
    const float* __restrict__ attn_w,
    const float* __restrict__ b_m0, const float* __restrict__ b_m1,
    const float* __restrict__ w_m2, const float* __restrict__ b_m2,
    const float* __restrict__ out_w, const float* __restrict__ out_b,
    const float* __restrict__ lat_tab, const float* __restrict__ lon_tab,
    const float* __restrict__ b3, const float* __restrict__ b5,
    const float* __restrict__ w4, const float* __restrict__ b4,
    const unsigned char*  __restrict__ emb4,   // fp4 table, 128 B/row
    const unsigned short* __restrict__ blob1,
    const unsigned short* __restrict__ blob2,
    const float* __restrict__ w3T, const float* __restrict__ w5T,
    float*       __restrict__ out)
{
    // arena: sort cnt/off; phase B = 8 waves x 2KB stage; phase C/D = h1+topk
    __shared__ __align__(16) unsigned char arena[16384];
    __shared__ __align__(16) unsigned short s_keys[LL][RR];   // 40 KB
    __shared__ __align__(8) unsigned short s_docs[RR];        // 4 KB sorted ids
    __shared__ float s_logit[LL];
    __shared__ float s_h[16];
    __shared__ float s_feat[164];

    unsigned short* s_h1   = (unsigned short*)arena;          // 4 KB (phase D)
    float*          s_topk = (float*)(arena + 4096);          // 2 KB (phase C/D)

    const int b    = blockIdx.x;
    const int tid  = threadIdx.x;
    const int lane = tid & 63;
    const int wid  = tid >> 6;
    const int m15  = lane & 15, q = lane >> 4;

    // ========= sort docs by id (bucket id>>7) for L2-local sweeping =========
    {
        unsigned* s_cnt = (unsigned*)arena;            // 256 u32 (phase-disjoint)
        unsigned* s_off = (unsigned*)(arena + 1024);   // 257 u32
        if (tid < 256) s_cnt[tid] = 0u;
        __syncthreads();
        const int* trb = text_right + b * RR;
        int dv[4];
        #pragma unroll
        for (int i = 0; i < 4; ++i) {
            dv[i] = trb[tid * 4 + i];
            atomicAdd(&s_cnt[dv[i] >> 7], 1u);
        }
        __syncthreads();
        if (tid < 256) s_off[tid + 1] = s_cnt[tid];
        if (tid == 0) s_off[0] = 0u;
        __syncthreads();
        #pragma unroll 1
        for (int st = 1; st < 256; st <<= 1) {
            unsigned v = 0u;
            if (tid < 256 && tid + 1 > st) v = s_off[tid + 1 - st];
            __syncthreads();
            if (tid < 256 && tid + 1 > st) s_off[tid + 1] += v;
            __syncthreads();
        }
        #pragma unroll
        for (int i = 0; i < 4; ++i) {
            unsigned p = atomicAdd(&s_off[dv[i] >> 7], 1u);
            s_docs[p] = (unsigned short)dv[i];
        }
        __syncthreads();
    }

    // ========= phase B: coalesced staged fp4 GEMM, banded tile order ========
    {
        // A fragments: call s uses row bytes [s*64 + q*16, +16)
        i32x8 a0, a1;
        {
            int qidx = (m15 < LL) ? text_left[b * LL + m15] : 0;
            const unsigned char* ap = emb4 + (size_t)qidx * 128;
            uint4 f0 = *(const uint4*)(ap + q * 16);
            uint4 f1 = *(const uint4*)(ap + 64 + q * 16);
            a0 = (i32x8){(int)f0.x, (int)f0.y, (int)f0.z, (int)f0.w, 0, 0, 0, 0};
            a1 = (i32x8){(int)f1.x, (int)f1.y, (int)f1.z, (int)f1.w, 0, 0, 0, 0};
        }
        const int r0 = lane >> 3;                // doc sub-row (0..7)
        const int c  = lane & 7;                 // 16B chunk within 128B row

        unsigned char* stg = arena + wid * 2048; // per-wave private buffer

        int  I0, I1;
        llx2 R0, R1;

        auto LOADI = [&](int i) {                // ids for tile step i
            int T = wid + 8 * i;
            I0 = (int)s_docs[T * 16 + r0];
            I1 = (int)s_docs[T * 16 + 8 + r0];
        };
        auto LOADR = [&]() {                     // rows (coalesced: 8 lanes/row)
            R0 = *(const llx2*)(emb4 + (size_t)I0 * 128 + (c << 4));
            R1 = *(const llx2*)(emb4 + (size_t)I1 * 128 + (c << 4));
        };
        auto STORE = [&]() {                     // regs -> LDS with XOR swizzle
            *(llx2*)(stg + r0 * 128 + ((c ^ r0) << 4))       = R0;
            *(llx2*)(stg + (8 + r0) * 128 + ((c ^ r0) << 4)) = R1;
        };
        auto COMPUTE = [&](int i) {
            uint4 b0 = *(const uint4*)(stg + m15 * 128 + ((q ^ (m15 & 7)) << 4));
            uint4 b1 = *(const uint4*)(stg + m15 * 128 + (((4 + q) ^ (m15 & 7)) << 4));
            i32x8 bb0 = {(int)b0.x, (int)b0.y, (int)b0.z, (int)b0.w, 0, 0, 0, 0};
            i32x8 bb1 = {(int)b1.x, (int)b1.y, (int)b1.z, (int)b1.w, 0, 0, 0, 0};
            f32x4 acc = {0.f, 0.f, 0.f, 0.f};
            acc = __builtin_amdgcn_mfma_scale_f32_16x16x128_f8f6f4(
                      a0, bb0, acc, 4, 4, 0, 0x7F7F7F7F, 0, 0x7F7F7F7F);
            acc = __builtin_amdgcn_mfma_scale_f32_16x16x128_f8f6f4(
                      a1, bb1, acc, 4, 4, 0, 0x7F7F7F7F, 0, 0x7F7F7F7F);
            int n0 = (wid + 8 * i) * 16;
            #pragma unroll
            for (int v = 0; v < 4; ++v) {
                int m = q * 4 + v;
                if (m < LL) {
                    float sc = acc[v] * FP4_DESCALE;
                    unsigned hb = (unsigned)__half_as_ushort(__float2half(sc));
                    unsigned ok = hb ^ ((hb & 0x8000u) ? 0xFFFFu : 0x8000u);
                    s_keys[m][n0 + m15] = (unsigned short)ok;
                }
            }
        };

        LOADI(0); LOADR(); LOADI(1);
        #pragma unroll 1
        for (int t = 0; t < 16; ++t) {
            STORE();                              // buf = tile step t
            if (t < 15) {
                LOADR();                          // issue rows(t+1), uses I
                if (t < 14) LOADI(t + 2);         // fetch idx(t+2)
            }
            COMPUTE(t);                           // overlaps in-flight loads
        }
    }
    __syncthreads();

    // pad-init topk cells never written by TOPK (rows>=10 or cols>=20)
    {
        int row = tid >> 5, col = tid & 31;
        if (row >= LL || col >= KK) s_topk[row * 32 + col] = 0.f;
    }

    // ====== phase C: top-k on all waves; aux work overlapped ================
    {
        auto TOPK_ROW = [&](int l) {
            const unsigned short* krow = &s_keys[l][0];
            unsigned extmask = 0u, k1, k2;
            build_top2(krow, lane, extmask, k1, k2);
            #pragma unroll 1
            for (int it = 0; it < KK; ++it) {
                unsigned bmk = wave_umax_u32(k1);
                if (k1 == bmk) {                  // unique owner (keys unique)
                    unsigned o16 = bmk >> 16;
                    unsigned hbv = (o16 & 0x8000u) ? (o16 & 0x7FFFu) : (o16 ^ 0xFFFFu);
                    s_topk[l * 32 + it] = __half2float(__ushort_as_half((unsigned short)hbv));
                    int j = 2047 - (int)(bmk & 0xFFFFu);
                    extmask |= 1u << (j >> 6);
                    k1 = k2; k2 = 0u;
                }
                if (__any(k1 == 0u)) {
                    if (k1 == 0u) build_top2(krow, lane, extmask, k1, k2);
                }
            }
        };
        TOPK_ROW(wid);                       // rows 0..7
        if (wid >= 6) {
            TOPK_ROW(wid + 2);               // rows 8,9
        } else if (wid == 4) {
            // attention logits
            const float4 aw = *(const float4*)(attn_w + lane * 4);
            for (int l = 0; l < LL; ++l) {
                int v = text_left[b * LL + l];
                float4 qv = *(const float4*)(emb + (size_t)v * DD + lane * 4);
                float d = qv.x * aw.x + qv.y * aw.y + qv.z * aw.z + qv.w * aw.w;
                #pragma unroll
                for (int off = 32; off; off >>= 1) d += __shfl_xor(d, off);
                if (lane == 0) s_logit[l] = (v == 0) ? -INFINITY : d;
            }
        } else if (wid == 5) {
            // geo features
            int c2 = lane & 31, which = lane >> 5;
            int v = loc_left[b * 2 + which];
            const float* tab = which ? lon_tab : lat_tab;
            const float4* tr = (const float4*)(tab + (size_t)v * GEOD);
            const float4* wr = (const float4*)(w5T + c2 * GEOD);
            float a = b5[c2];
            #pragma unroll
            for (int d4 = 0; d4 < 16; ++d4) {
                float4 tv = tr[d4], wv = wr[d4];
                a += tv.x * wv.x + tv.y * wv.y + tv.z * wv.z + tv.w * wv.w;
            }
            s_feat[100 + which * 32 + c2] = a;
        } else if (wid == 2 || wid == 3) {
            // q1 projection features
            int p = (wid - 2) * 64 + lane;
            if (p < 100) {
                int l = p / 10, j = p % 10;
                int v = text_left[b * LL + l];
                const float4* qr = (const float4*)(emb + (size_t)v * DD);
                const float4* wr = (const float4*)(w3T + j * DD);
                float a = b3[j];
                #pragma unroll 8
                for (int d4 = 0; d4 < 64; ++d4) {
                    float4 qv = qr[d4], wv = wr[d4];
                    a += qv.x * wv.x + qv.y * wv.y + qv.z * wv.z + qv.w * wv.w;
                }
                s_feat[p] = a;
            }
        }
    }
    __syncthreads();

    // ================= phase D: MFMA MLP + softmax + output (wave 0) ========
    if (wid == 0) {
        // ---- layer 1: topk[16x32] @ w_m0 -> h1[16x128] ----
        float tv[8];
        *(float4*)(tv)     = *(const float4*)(&s_topk[m15 * 32 + q * 8]);
        *(float4*)(tv + 4) = *(const float4*)(&s_topk[m15 * 32 + q * 8 + 4]);
        bf16x8 a1;
        #pragma unroll
        for (int t = 0; t < 8; ++t) a1[t] = (short)f2bf(tv[t]);
        f32x4 acc1[8];
        #pragma unroll
        for (int t = 0; t < 8; ++t) {
            bf16x8 b1 = *(const bf16x8*)(blob1 + t * 512 + lane * 8);
            f32x4 z = {0.f, 0.f, 0.f, 0.f};
            acc1[t] = __builtin_amdgcn_mfma_f32_16x16x32_bf16(a1, b1, z, 0, 0, 0);
        }
        #pragma unroll
        for (int t = 0; t < 8; ++t) {
            int c = t * 16 + m15;
            float bb0 = b_m0[c];
            #pragma unroll
            for (int v = 0; v < 4; ++v) {
                int m = q * 4 + v;
                float h = tanhf(acc1[t][v] + bb0);
                s_h1[m * 128 + (((c >> 3) ^ m) << 3) + (c & 7)] = f2bf(h);
            }
        }
        // ---- layer 2 ----
        f32x4 acc2[8];
        #pragma unroll
        for (int t = 0; t < 8; ++t) acc2[t] = (f32x4){0.f, 0.f, 0.f, 0.f};
        #pragma unroll
        for (int ks = 0; ks < 4; ++ks) {
            bf16x8 a2 = *(const bf16x8*)(s_h1 + m15 * 128 + (((ks * 4 + q) ^ m15) << 3));
            #pragma unroll
            for (int t = 0; t < 8; ++t) {
                bf16x8 b2 = *(const bf16x8*)(blob2 + (ks * 8 + t) * 512 + lane * 8);
                acc2[t] = __builtin_amdgcn_mfma_f32_16x16x32_bf16(a2, b2, acc2[t], 0, 0, 0);
            }
        }
        // ---- layer 3 + reduce ----
        float part[4] = {0.f, 0.f, 0.f, 0.f};
        #pragma unroll
        for (int t = 0; t < 8; ++t) {
            int c = t * 16 + m15;
            float bb1 = b_m1[c];
            float wm2 = w_m2[c];
            #pragma unroll
            for (int v = 0; v < 4; ++v)
                part[v] += tanhf(acc2[t][v] + bb1) * wm2;
        }
        #pragma unroll
        for (int v = 0; v < 4; ++v) {
            #pragma unroll
            for (int off = 1; off < 16; off <<= 1) part[v] += __shfl_xor(part[v], off);
        }
        if (m15 == 0) {
            #pragma unroll
            for (int v = 0; v < 4; ++v) {
                int m = q * 4 + v;
                if (m < LL) s_h[m] = tanhf(part[v] + b_m2[0]);
            }
        }
        // ---- parallel 164-dot for w0/w1 across the wave ----
        float w0p = 0.f, w1p = 0.f;
        #pragma unroll
        for (int i = lane; i < 164; i += 64) {
            float f = s_feat[i];
            w0p += f * w4[i * 2 + 0];
            w1p += f * w4[i * 2 + 1];
        }
        #pragma unroll
        for (int off = 32; off; off >>= 1) {
            w0p += __shfl_xor(w0p, off);
            w1p += __shfl_xor(w1p, off);
        }
        // ---- softmax + frozen x + final output (lane 0) ----
        if (lane == 0) {
            float mx = -INFINITY;
            #pragma unroll
            for (int l = 0; l < LL; ++l) mx = fmaxf(mx, s_logit[l]);
            float ex[LL];
            float sum = 0.f;
            #pragma unroll
            for (int l = 0; l < LL; ++l) { ex[l] = expf(s_logit[l] - mx); sum += ex[l]; }
            float x = 0.f;
            #pragma unroll
            for (int l = 0; l < LL; ++l) x += s_h[l] * (ex[l] / sum);
            float xo = tanhf(x * out_w[0] + out_b[0]);
            out[b] = (w0p + b4[0]) * xo + (w1p + b4[1]) * distance[b];
        }
    }
}

extern "C" void kernel_launch(void* const* d_in, const int* in_sizes, int n_in,
                              void* d_out, int out_size, void* d_ws, size_t ws_size,
                              hipStream_t stream) {
    const int*   text_left  = (const int*)  d_in[0];
    const int*   text_right = (const int*)  d_in[1];
    const int*   loc_left   = (const int*)  d_in[2];
    const float* distance   = (const float*)d_in[3];
    const float* emb        = (const float*)d_in[4];
    const float* attn_w     = (const float*)d_in[5];
    const float* w_m0       = (const float*)d_in[6];
    const float* b_m0       = (const float*)d_in[7];
    const float* w_m1       = (const float*)d_in[8];
    const float* b_m1       = (const float*)d_in[9];
    const float* w_m2       = (const float*)d_in[10];
    const float* b_m2       = (const float*)d_in[11];
    const float* out_w      = (const float*)d_in[12];
    const float* out_b      = (const float*)d_in[13];
    const float* lat_tab    = (const float*)d_in[14];
    const float* lon_tab    = (const float*)d_in[15];
    const float* w3         = (const float*)d_in[16];
    const float* b3         = (const float*)d_in[17];
    const float* w5         = (const float*)d_in[18];
    const float* b5         = (const float*)d_in[19];
    const float* w4         = (const float*)d_in[20];
    const float* b4         = (const float*)d_in[21];

    unsigned char*  ws    = (unsigned char*)d_ws;
    unsigned char*  emb4  = ws;
    unsigned short* blob1 = (unsigned short*)(ws + BLOB1_OFF);
    unsigned short* blob2 = (unsigned short*)(ws + BLOB2_OFF);
    float*          w3T   = (float*)(ws + W3T_OFF);
    float*          w5T   = (float*)(ws + W5T_OFF);
    float*          out   = (float*)d_out;

    pre_kernel<<<7598, 256, 0, stream>>>(emb, w_m0, w_m1, w3, w5,
                                         emb4, blob1, blob2, w3T, w5T);

    fused_kernel<<<BB, 512, 0, stream>>>(
        text_left, text_right, loc_left, distance, emb, attn_w,
        b_m0, b_m1, w_m2, b_m2, out_w, out_b,
        lat_tab, lon_tab, b3, b5, w4, b4,
        emb4, blob1, blob2, w3T, w5T, out);
}